// Round 1
// baseline (738.595 us; speedup 1.0000x reference)
//
#include <hip/hip_runtime.h>

#define N_NODES 50000
#define N_EDGES 800000
#define DIM     128
#define CAP     64
#define NGRAPH  128
#define NCLASS  10
#define N_HID   3

// ---------------------------------------------------------------------------
// Build bucket-CSR: per-edge, histogram out-degree (src) and in-degree (dst),
// scatter src index into dst's fixed-stride bucket.
__global__ __launch_bounds__(256) void build_kernel(
    const int* __restrict__ ei, unsigned* __restrict__ out_deg,
    unsigned* __restrict__ cnt_in, unsigned* __restrict__ col)
{
    int e = blockIdx.x * blockDim.x + threadIdx.x;
    if (e >= N_EDGES) return;
    int s = ei[e];
    int d = ei[N_EDGES + e];
    atomicAdd(&out_deg[s], 1u);
    unsigned pos = atomicAdd(&cnt_in[d], 1u);
    if (pos < CAP) col[(size_t)d * CAP + pos] = (unsigned)s;
}

// c_src = clip(out_deg,1)^-0.5 ; c_dst = clip(in_deg,1)^-0.5
__global__ __launch_bounds__(256) void norm_kernel(
    const unsigned* __restrict__ out_deg, const unsigned* __restrict__ cnt_in,
    float* __restrict__ c_src, float* __restrict__ c_dst)
{
    int i = blockIdx.x * blockDim.x + threadIdx.x;
    if (i >= N_NODES) return;
    unsigned od = out_deg[i]; if (od < 1u) od = 1u;
    unsigned id_ = cnt_in[i]; if (id_ < 1u) id_ = 1u;
    c_src[i] = 1.0f / sqrtf((float)od);
    c_dst[i] = 1.0f / sqrtf((float)id_);
}

// hs = x * c_src[row]  (float4 vectorized)
__global__ __launch_bounds__(256) void prescale_kernel(
    const float4* __restrict__ x, const float* __restrict__ c_src,
    float4* __restrict__ hs)
{
    int i = blockIdx.x * blockDim.x + threadIdx.x;   // over N*32 float4s
    if (i >= N_NODES * (DIM / 4)) return;
    int row = i >> 5;                                 // /(DIM/4)
    float c = c_src[row];
    float4 v = x[i];
    v.x *= c; v.y *= c; v.z *= c; v.w *= c;
    hs[i] = v;
}

// m[n] = sum over in-edges of hs[src]. One wave per node, lane holds float2.
__global__ __launch_bounds__(256) void aggregate_kernel(
    const float2* __restrict__ hs, const unsigned* __restrict__ col,
    const unsigned* __restrict__ cnt_in, float2* __restrict__ m,
    int total_waves)
{
    int wid  = (blockIdx.x * blockDim.x + threadIdx.x) >> 6;
    int lane = threadIdx.x & 63;
    for (int n = wid; n < N_NODES; n += total_waves) {
        unsigned deg = cnt_in[n]; if (deg > CAP) deg = CAP;
        const unsigned* cl = col + (size_t)n * CAP;
        float2 acc; acc.x = 0.f; acc.y = 0.f;
        for (unsigned t = 0; t < deg; ++t) {
            unsigned s = cl[t];
            float2 v = hs[(size_t)s * (DIM / 2) + lane];
            acc.x += v.x; acc.y += v.y;
        }
        m[(size_t)n * (DIM / 2) + lane] = acc;
    }
}

// Hout = relu(c_dst[r] * (M @ W) + b) * (scale_out ? c_src[r] : 1)
// Block: 256 threads -> 128x128 tile (all cols). 8x8 register tile/thread.
__global__ __launch_bounds__(256) void gemm_relu_kernel(
    const float* __restrict__ M, const float* __restrict__ W,
    const float* __restrict__ bias, const float* __restrict__ c_dst,
    const float* __restrict__ c_src, float* __restrict__ Hout,
    int scale_out)
{
    __shared__ float sW[DIM * DIM];        // 64 KB
    __shared__ float sM[DIM * 17];         // 128 rows x 16 k, pad 17
    __shared__ float sB[DIM];

    int tid = threadIdx.x;
    int tx  = tid & 15;        // col group: cols tx*8 .. tx*8+7
    int ty  = tid >> 4;        // row group: rows ty*8 .. ty*8+7
    int row0 = blockIdx.x * DIM;

    // stage W (+bias) into LDS
    const float4* W4 = (const float4*)W;
    float4* sW4 = (float4*)sW;
    for (int i = tid; i < DIM * DIM / 4; i += 256) sW4[i] = W4[i];
    if (tid < DIM) sB[tid] = bias[tid];

    float acc[8][8];
#pragma unroll
    for (int i = 0; i < 8; ++i)
#pragma unroll
        for (int j = 0; j < 8; ++j) acc[i][j] = 0.f;

    for (int kk = 0; kk < DIM; kk += 16) {
        // load M chunk: 128 rows x 16 cols = 512 float4s, 2 per thread
        for (int i = tid; i < 512; i += 256) {
            int r = i >> 2, s = i & 3;
            int gr = row0 + r;
            float4 v;
            if (gr < N_NODES) v = *(const float4*)(M + (size_t)gr * DIM + kk + s * 4);
            else { v.x = v.y = v.z = v.w = 0.f; }
            float* dp = &sM[r * 17 + s * 4];
            dp[0] = v.x; dp[1] = v.y; dp[2] = v.z; dp[3] = v.w;
        }
        __syncthreads();
#pragma unroll
        for (int k = 0; k < 16; ++k) {
            float a[8];
#pragma unroll
            for (int i = 0; i < 8; ++i) a[i] = sM[(ty * 8 + i) * 17 + k];
            const float* wr = &sW[(kk + k) * DIM + tx * 8];
            float4 w0 = *(const float4*)wr;
            float4 w1 = *(const float4*)(wr + 4);
            float b[8] = {w0.x, w0.y, w0.z, w0.w, w1.x, w1.y, w1.z, w1.w};
#pragma unroll
            for (int i = 0; i < 8; ++i)
#pragma unroll
                for (int j = 0; j < 8; ++j) acc[i][j] = fmaf(a[i], b[j], acc[i][j]);
        }
        __syncthreads();
    }

    // epilogue
#pragma unroll
    for (int i = 0; i < 8; ++i) {
        int gr = row0 + ty * 8 + i;
        if (gr >= N_NODES) break;
        float cd = c_dst[gr];
        float cs = scale_out ? c_src[gr] : 1.0f;
        float out[8];
#pragma unroll
        for (int j = 0; j < 8; ++j) {
            float v = acc[i][j] * cd + sB[tx * 8 + j];
            v = v > 0.f ? v : 0.f;
            out[j] = v * cs;
        }
        float4* dst = (float4*)(Hout + (size_t)gr * DIM + tx * 8);
        dst[0] = make_float4(out[0], out[1], out[2], out[3]);
        dst[1] = make_float4(out[4], out[5], out[6], out[7]);
    }
}

// Mean-pool readout: graph_ids sorted -> run-length local accumulate, flush
// one atomic per (graph-run, feature). Block = 128 threads (one per feature),
// each block covers 64 consecutive nodes.
__global__ __launch_bounds__(128) void readout_kernel(
    const float* __restrict__ h, const int* __restrict__ gid,
    float* __restrict__ hg, float* __restrict__ cntg)
{
    int j  = threadIdx.x;
    int n0 = blockIdx.x * 64;
    float acc = 0.f; int cur = -1; int run = 0;
    for (int i = 0; i < 64; ++i) {
        int n = n0 + i;
        if (n >= N_NODES) break;
        int g = gid[n];
        if (g != cur) {
            if (cur >= 0) {
                atomicAdd(&hg[cur * DIM + j], acc);
                if (j == 0) atomicAdd(&cntg[cur], (float)run);
            }
            cur = g; acc = 0.f; run = 0;
        }
        acc += h[(size_t)n * DIM + j];
        run++;
    }
    if (cur >= 0) {
        atomicAdd(&hg[cur * DIM + j], acc);
        if (j == 0) atomicAdd(&cntg[cur], (float)run);
    }
}

// out[g,c] = (hg[g]/cnt[g]) @ Wc + bc
__global__ __launch_bounds__(256) void head_kernel(
    const float* __restrict__ hg, const float* __restrict__ cntg,
    const float* __restrict__ Wc, const float* __restrict__ bc,
    float* __restrict__ out)
{
    int idx = blockIdx.x * blockDim.x + threadIdx.x;
    if (idx >= NGRAPH * NCLASS) return;
    int g = idx / NCLASS, c = idx % NCLASS;
    float inv = 1.0f / fmaxf(cntg[g], 1.0f);
    float s = 0.f;
    for (int j = 0; j < DIM; ++j) s = fmaf(hg[g * DIM + j], Wc[j * NCLASS + c], s);
    out[idx] = s * inv + bc[c];
}

// ---------------------------------------------------------------------------
extern "C" void kernel_launch(void* const* d_in, const int* in_sizes, int n_in,
                              void* d_out, int out_size, void* d_ws, size_t ws_size,
                              hipStream_t stream)
{
    const float* x   = (const float*)d_in[0];
    const float* W0  = (const float*)d_in[1];
    const float* b0  = (const float*)d_in[2];
    const float* Ws  = (const float*)d_in[3];
    const float* bs  = (const float*)d_in[4];
    const float* Wc  = (const float*)d_in[5];
    const float* bc  = (const float*)d_in[6];
    const int*   ei  = (const int*)d_in[7];
    const int*   gid = (const int*)d_in[8];
    float* out = (float*)d_out;

    char* ws = (char*)d_ws;
    size_t o = 0;
    auto alloc = [&](size_t bytes) {
        size_t r = o; o = (o + bytes + 255) & ~(size_t)255; return r;
    };
    unsigned* cnt_in  = (unsigned*)(ws + alloc((size_t)N_NODES * 4));
    unsigned* out_deg = (unsigned*)(ws + alloc((size_t)N_NODES * 4));
    float*    c_src   = (float*)(ws + alloc((size_t)N_NODES * 4));
    float*    c_dst   = (float*)(ws + alloc((size_t)N_NODES * 4));
    unsigned* col     = (unsigned*)(ws + alloc((size_t)N_NODES * CAP * 4));
    float*    hs      = (float*)(ws + alloc((size_t)N_NODES * DIM * 4));
    float*    mbuf    = (float*)(ws + alloc((size_t)N_NODES * DIM * 4));
    float*    hg      = (float*)(ws + alloc((size_t)NGRAPH * DIM * 4));
    float*    cntg    = (float*)(ws + alloc((size_t)NGRAPH * 4));

    // zero the accumulated buffers (ws is poisoned 0xAA before every call)
    hipMemsetAsync(cnt_in,  0, (size_t)N_NODES * 4, stream);
    hipMemsetAsync(out_deg, 0, (size_t)N_NODES * 4, stream);
    hipMemsetAsync(hg,      0, (size_t)NGRAPH * DIM * 4, stream);
    hipMemsetAsync(cntg,    0, (size_t)NGRAPH * 4, stream);

    build_kernel<<<(N_EDGES + 255) / 256, 256, 0, stream>>>(ei, out_deg, cnt_in, col);
    norm_kernel<<<(N_NODES + 255) / 256, 256, 0, stream>>>(out_deg, cnt_in, c_src, c_dst);
    prescale_kernel<<<(N_NODES * (DIM / 4) + 255) / 256, 256, 0, stream>>>(
        (const float4*)x, c_src, (float4*)hs);

    const int AGG_BLOCKS = 2048;
    const int TOTAL_WAVES = AGG_BLOCKS * 4;
    const int GEMM_BLOCKS = (N_NODES + DIM - 1) / DIM;

    for (int l = 0; l < 1 + N_HID; ++l) {
        const float* W = (l == 0) ? W0 : (Ws + (size_t)(l - 1) * DIM * DIM);
        const float* b = (l == 0) ? b0 : (bs + (size_t)(l - 1) * DIM);
        int scale_out = (l < N_HID) ? 1 : 0;   // last layer output stays unscaled
        aggregate_kernel<<<AGG_BLOCKS, 256, 0, stream>>>(
            (const float2*)hs, col, cnt_in, (float2*)mbuf, TOTAL_WAVES);
        gemm_relu_kernel<<<GEMM_BLOCKS, 256, 0, stream>>>(
            mbuf, W, b, c_dst, c_src, hs, scale_out);
    }

    readout_kernel<<<(N_NODES + 63) / 64, 128, 0, stream>>>(hs, gid, hg, cntg);
    head_kernel<<<(NGRAPH * NCLASS + 255) / 256, 256, 0, stream>>>(hg, cntg, Wc, bc, out);
}

// Round 2
// 575.725 us; speedup vs baseline: 1.2829x; 1.2829x over previous
//
#include <hip/hip_runtime.h>

#define N_NODES 50000
#define N_EDGES 800000
#define DIM     128
#define CAP     64
#define NGRAPH  128
#define NCLASS  10
#define N_HID   3
#define NLAYER  4

typedef __attribute__((ext_vector_type(8))) short short8;
typedef __attribute__((ext_vector_type(4))) float floatx4;

__device__ __forceinline__ unsigned f2bf(float f) {
    union { float f; unsigned u; } v; v.f = f;
    return (v.u + 0x7fffu + ((v.u >> 16) & 1u)) >> 16;   // RNE
}
__device__ __forceinline__ float bf_lo(unsigned u) { return __uint_as_float(u << 16); }
__device__ __forceinline__ float bf_hi(unsigned u) { return __uint_as_float(u & 0xffff0000u); }

// ---------------------------------------------------------------------------
// Build bucket-CSR: histogram degrees, scatter src into dst's bucket.
__global__ __launch_bounds__(256) void build_kernel(
    const int* __restrict__ ei, unsigned* __restrict__ out_deg,
    unsigned* __restrict__ cnt_in, unsigned* __restrict__ col)
{
    int e = blockIdx.x * blockDim.x + threadIdx.x;
    if (e >= N_EDGES) return;
    int s = ei[e];
    int d = ei[N_EDGES + e];
    atomicAdd(&out_deg[s], 1u);
    unsigned pos = atomicAdd(&cnt_in[d], 1u);
    if (pos < CAP) col[(size_t)d * CAP + pos] = (unsigned)s;
}

__global__ __launch_bounds__(256) void norm_kernel(
    const unsigned* __restrict__ out_deg, const unsigned* __restrict__ cnt_in,
    float* __restrict__ c_src, float* __restrict__ c_dst)
{
    int i = blockIdx.x * blockDim.x + threadIdx.x;
    if (i >= N_NODES) return;
    unsigned od = out_deg[i]; if (od < 1u) od = 1u;
    unsigned id_ = cnt_in[i]; if (id_ < 1u) id_ = 1u;
    c_src[i] = 1.0f / sqrtf((float)od);
    c_dst[i] = 1.0f / sqrtf((float)id_);
}

// hs(bf16 pairs) = x * c_src[row]
__global__ __launch_bounds__(256) void prescale_kernel(
    const float2* __restrict__ x, const float* __restrict__ c_src,
    unsigned* __restrict__ hs)
{
    int i = blockIdx.x * blockDim.x + threadIdx.x;   // over N*64 uints
    if (i >= N_NODES * 64) return;
    int row = i >> 6;
    float c = c_src[row];
    float2 v = x[i];
    hs[i] = f2bf(v.x * c) | (f2bf(v.y * c) << 16);
}

// m[n] = sum over in-edges of hs[src]; bf16 rows (256B), fp32 accumulate.
__global__ __launch_bounds__(256) void aggregate_kernel(
    const unsigned* __restrict__ hs, const unsigned* __restrict__ col,
    const unsigned* __restrict__ cnt_in, unsigned* __restrict__ m,
    int total_waves)
{
    int wid  = (blockIdx.x * blockDim.x + threadIdx.x) >> 6;
    int lane = threadIdx.x & 63;
    for (int n = wid; n < N_NODES; n += total_waves) {
        unsigned deg = cnt_in[n]; if (deg > CAP) deg = CAP;
        const unsigned* cl = col + (size_t)n * CAP;
        float ax = 0.f, ay = 0.f;
        for (unsigned t = 0; t < deg; ++t) {
            unsigned s = cl[t];
            unsigned u = hs[(size_t)s * 64 + lane];
            ax += bf_lo(u); ay += bf_hi(u);
        }
        m[(size_t)n * 64 + lane] = f2bf(ax) | (f2bf(ay) << 16);
    }
}

// Pre-swizzle W into MFMA B-fragment order, bf16.
// Frag index: [(c*4+s)*64 + lane] (uint4 = 8 bf16 = W[k0+j][colw], j=0..7),
// k0 = s*32 + (lane>>4)*8, colw = c*16 + (lane&15).
__global__ __launch_bounds__(256) void wprep_kernel(
    const float* __restrict__ W0, const float* __restrict__ Ws,
    uint4* __restrict__ Wf)
{
    int t = blockIdx.x * blockDim.x + threadIdx.x;
    if (t >= NLAYER * 2048) return;
    int layer = t >> 11;
    int rem = t & 2047;
    int lane = rem & 63;
    int s = (rem >> 6) & 3;
    int c = rem >> 8;
    int quad = lane >> 4, colw = c * 16 + (lane & 15);
    int k0 = s * 32 + quad * 8;
    const float* W = (layer == 0) ? W0 : Ws + (size_t)(layer - 1) * DIM * DIM;
    uint4 p;
    unsigned* pp = (unsigned*)&p;
#pragma unroll
    for (int j = 0; j < 4; ++j) {
        unsigned lo = f2bf(W[(size_t)(k0 + 2 * j) * DIM + colw]);
        unsigned hi = f2bf(W[(size_t)(k0 + 2 * j + 1) * DIM + colw]);
        pp[j] = lo | (hi << 16);
    }
    Wf[t] = p;
}

// Hout = relu(c_dst[r]*(M@W) + b) [* c_src[r] if !last], MFMA 16x16x32 bf16.
// Block = 4 waves, each wave 16 rows x 128 cols. No LDS.
__global__ __launch_bounds__(256) void mfma_gemm_kernel(
    const uint4* __restrict__ Mb, const uint4* __restrict__ Wf,
    const float* __restrict__ bias, const float* __restrict__ c_dst,
    const float* __restrict__ c_src, unsigned short* __restrict__ out_bf,
    float* __restrict__ out_f32, int last)
{
    int tid = threadIdx.x;
    int wave = tid >> 6, lane = tid & 63;
    int quad = lane >> 4, m16 = lane & 15;
    int r0 = blockIdx.x * 64 + wave * 16;

    int rA = r0 + m16; if (rA >= N_NODES) rA = N_NODES - 1;
    const uint4* pA = Mb + (size_t)rA * 16 + quad;   // row=256B=16 uint4
    union U { uint4 u; short8 s; };
    U a[4];
#pragma unroll
    for (int s = 0; s < 4; ++s) a[s].u = pA[s * 4];  // k-window stride 64B

    floatx4 acc[8];
#pragma unroll
    for (int c = 0; c < 8; ++c) {
        floatx4 ac = {0.f, 0.f, 0.f, 0.f};
#pragma unroll
        for (int s = 0; s < 4; ++s) {
            U b; b.u = Wf[(c * 4 + s) * 64 + lane];
            ac = __builtin_amdgcn_mfma_f32_16x16x32_bf16(a[s].s, b.s, ac, 0, 0, 0);
        }
        acc[c] = ac;
    }

    // C/D layout: col = lane&15, row = quad*4 + reg
    float cd[4], cs[4];
    int rows[4];
#pragma unroll
    for (int r = 0; r < 4; ++r) {
        int row = r0 + quad * 4 + r; rows[r] = row;
        bool ok = row < N_NODES;
        cd[r] = ok ? c_dst[row] : 0.f;
        cs[r] = (ok && !last) ? c_src[row] : 1.f;
    }
#pragma unroll
    for (int c = 0; c < 8; ++c) {
        int colg = c * 16 + m16;
        float b = bias[colg];
#pragma unroll
        for (int r = 0; r < 4; ++r) {
            int row = rows[r];
            if (row >= N_NODES) continue;
            float v = acc[c][r] * cd[r] + b;
            v = v > 0.f ? v : 0.f;
            if (last) out_f32[(size_t)row * DIM + colg] = v;
            else      out_bf[(size_t)row * DIM + colg] = (unsigned short)f2bf(v * cs[r]);
        }
    }
}

// Mean-pool readout on sorted graph_ids (fp32 h).
__global__ __launch_bounds__(128) void readout_kernel(
    const float* __restrict__ h, const int* __restrict__ gid,
    float* __restrict__ hg, float* __restrict__ cntg)
{
    int j  = threadIdx.x;
    int n0 = blockIdx.x * 64;
    float acc = 0.f; int cur = -1; int run = 0;
    for (int i = 0; i < 64; ++i) {
        int n = n0 + i;
        if (n >= N_NODES) break;
        int g = gid[n];
        if (g != cur) {
            if (cur >= 0) {
                atomicAdd(&hg[cur * DIM + j], acc);
                if (j == 0) atomicAdd(&cntg[cur], (float)run);
            }
            cur = g; acc = 0.f; run = 0;
        }
        acc += h[(size_t)n * DIM + j];
        run++;
    }
    if (cur >= 0) {
        atomicAdd(&hg[cur * DIM + j], acc);
        if (j == 0) atomicAdd(&cntg[cur], (float)run);
    }
}

__global__ __launch_bounds__(256) void head_kernel(
    const float* __restrict__ hg, const float* __restrict__ cntg,
    const float* __restrict__ Wc, const float* __restrict__ bc,
    float* __restrict__ out)
{
    int idx = blockIdx.x * blockDim.x + threadIdx.x;
    if (idx >= NGRAPH * NCLASS) return;
    int g = idx / NCLASS, c = idx % NCLASS;
    float inv = 1.0f / fmaxf(cntg[g], 1.0f);
    float s = 0.f;
    for (int j = 0; j < DIM; ++j) s = fmaf(hg[g * DIM + j], Wc[j * NCLASS + c], s);
    out[idx] = s * inv + bc[c];
}

// ---------------------------------------------------------------------------
extern "C" void kernel_launch(void* const* d_in, const int* in_sizes, int n_in,
                              void* d_out, int out_size, void* d_ws, size_t ws_size,
                              hipStream_t stream)
{
    const float* x   = (const float*)d_in[0];
    const float* W0  = (const float*)d_in[1];
    const float* b0  = (const float*)d_in[2];
    const float* Ws  = (const float*)d_in[3];
    const float* bs  = (const float*)d_in[4];
    const float* Wc  = (const float*)d_in[5];
    const float* bc  = (const float*)d_in[6];
    const int*   ei  = (const int*)d_in[7];
    const int*   gid = (const int*)d_in[8];
    float* out = (float*)d_out;

    char* ws = (char*)d_ws;
    size_t o = 0;
    auto alloc = [&](size_t bytes) {
        size_t r = o; o = (o + bytes + 255) & ~(size_t)255; return r;
    };
    unsigned* cnt_in  = (unsigned*)(ws + alloc((size_t)N_NODES * 4));
    unsigned* out_deg = (unsigned*)(ws + alloc((size_t)N_NODES * 4));
    float*    c_src   = (float*)(ws + alloc((size_t)N_NODES * 4));
    float*    c_dst   = (float*)(ws + alloc((size_t)N_NODES * 4));
    unsigned* col     = (unsigned*)(ws + alloc((size_t)N_NODES * CAP * 4));
    unsigned* hs      = (unsigned*)(ws + alloc((size_t)N_NODES * 64 * 4));  // bf16 x2
    unsigned* mbuf    = (unsigned*)(ws + alloc((size_t)N_NODES * 64 * 4));  // bf16 x2
    float*    hlast   = (float*)(ws + alloc((size_t)N_NODES * DIM * 4));
    uint4*    Wf      = (uint4*)(ws + alloc((size_t)NLAYER * 2048 * 16));
    float*    hg      = (float*)(ws + alloc((size_t)NGRAPH * DIM * 4));
    float*    cntg    = (float*)(ws + alloc((size_t)NGRAPH * 4));

    hipMemsetAsync(cnt_in,  0, (size_t)N_NODES * 4, stream);
    hipMemsetAsync(out_deg, 0, (size_t)N_NODES * 4, stream);
    hipMemsetAsync(hg,      0, (size_t)NGRAPH * DIM * 4, stream);
    hipMemsetAsync(cntg,    0, (size_t)NGRAPH * 4, stream);

    build_kernel<<<(N_EDGES + 255) / 256, 256, 0, stream>>>(ei, out_deg, cnt_in, col);
    norm_kernel<<<(N_NODES + 255) / 256, 256, 0, stream>>>(out_deg, cnt_in, c_src, c_dst);
    prescale_kernel<<<(N_NODES * 64 + 255) / 256, 256, 0, stream>>>(
        (const float2*)x, c_src, hs);
    wprep_kernel<<<(NLAYER * 2048 + 255) / 256, 256, 0, stream>>>(W0, Ws, Wf);

    const int AGG_BLOCKS = 2048;
    const int TOTAL_WAVES = AGG_BLOCKS * 4;
    const int GEMM_BLOCKS = (N_NODES + 63) / 64;

    for (int l = 0; l < NLAYER; ++l) {
        const float* b = (l == 0) ? b0 : (bs + (size_t)(l - 1) * DIM);
        int last = (l == NLAYER - 1) ? 1 : 0;
        aggregate_kernel<<<AGG_BLOCKS, 256, 0, stream>>>(hs, col, cnt_in, mbuf, TOTAL_WAVES);
        mfma_gemm_kernel<<<GEMM_BLOCKS, 256, 0, stream>>>(
            (const uint4*)mbuf, Wf + (size_t)l * 2048, b, c_dst, c_src,
            (unsigned short*)hs, hlast, last);
    }

    readout_kernel<<<(N_NODES + 63) / 64, 128, 0, stream>>>(hlast, gid, hg, cntg);
    head_kernel<<<(NGRAPH * NCLASS + 255) / 256, 256, 0, stream>>>(hg, cntg, Wc, bc, out);
}

// Round 3
// 428.259 us; speedup vs baseline: 1.7246x; 1.3443x over previous
//
#include <hip/hip_runtime.h>

#define N_NODES 50000
#define N_EDGES 800000
#define DIM     128
#define NGRAPH  128
#define NCLASS  10
#define N_HID   3
#define NLAYER  4

#define TEAMS   4
#define TCAP    24          // per-(node,team) bucket cap; Poisson(4) tail ~1e-12
#define CAPD    64          // dense bucket cap; Poisson(16) tail ~1e-18
#define NBT     64          // node-range blocks per team
#define RNG     782         // ceil(N_NODES / NBT)

typedef __attribute__((ext_vector_type(8))) short short8;
typedef __attribute__((ext_vector_type(4))) float floatx4;

__device__ __forceinline__ unsigned f2bf(float f) {
    union { float f; unsigned u; } v; v.f = f;
    return (v.u + 0x7fffu + ((v.u >> 16) & 1u)) >> 16;   // RNE
}
__device__ __forceinline__ float bf_lo(unsigned u) { return __uint_as_float(u << 16); }
__device__ __forceinline__ float bf_hi(unsigned u) { return __uint_as_float(u & 0xffff0000u); }

// ---------------------------------------------------------------------------
// Privatized counting-sort build. Grid = TEAMS*NBT blocks x 1024.
// Block (team, nb): scans team's edge quarter; LDS-histograms src/dst within
// its 782-node range; scatters col entries into per-team sub-buckets.
__global__ __launch_bounds__(1024) void part_build_kernel(
    const int* __restrict__ ei, unsigned* __restrict__ out4,
    unsigned* __restrict__ in4, unsigned* __restrict__ col4)
{
    __shared__ unsigned loc_in[RNG], loc_out[RNG];
    int team = blockIdx.x & (TEAMS - 1);
    int nb   = blockIdx.x >> 2;
    int lo = nb * RNG;
    int hi = lo + RNG; if (hi > N_NODES) hi = N_NODES;
    for (int i = threadIdx.x; i < RNG; i += 1024) { loc_in[i] = 0; loc_out[i] = 0; }
    __syncthreads();

    const int e0 = team * (N_EDGES / TEAMS);
    const int e1 = e0 + (N_EDGES / TEAMS);
    const int* __restrict__ srcp = ei;
    const int* __restrict__ dstp = ei + N_EDGES;
    for (int e = e0 + threadIdx.x; e < e1; e += 1024) {
        int s = srcp[e];
        int d = dstp[e];
        if (s >= lo && s < hi) atomicAdd(&loc_out[s - lo], 1u);
        if (d >= lo && d < hi) {
            unsigned pos = atomicAdd(&loc_in[d - lo], 1u);
            if (pos < TCAP)
                col4[(size_t)d * (TEAMS * TCAP) + team * TCAP + pos] = (unsigned)s;
        }
    }
    __syncthreads();

    for (int i = threadIdx.x; i < RNG; i += 1024) {
        int n = lo + i;
        if (n < N_NODES) {
            in4 [team * N_NODES + n] = loc_in[i];
            out4[team * N_NODES + n] = loc_out[i];
        }
    }
}

// Sum team partials -> degrees -> norm coefficients + total in-deg.
__global__ __launch_bounds__(256) void norm_kernel(
    const unsigned* __restrict__ out4, const unsigned* __restrict__ in4,
    float* __restrict__ c_src, float* __restrict__ c_dst,
    unsigned* __restrict__ cnt_tot)
{
    int i = blockIdx.x * blockDim.x + threadIdx.x;
    if (i >= N_NODES) return;
    unsigned od = out4[i] + out4[N_NODES + i] + out4[2 * N_NODES + i] + out4[3 * N_NODES + i];
    unsigned id_ = in4[i] + in4[N_NODES + i] + in4[2 * N_NODES + i] + in4[3 * N_NODES + i];
    cnt_tot[i] = id_;
    if (od < 1u) od = 1u;
    if (id_ < 1u) id_ = 1u;
    c_src[i] = 1.0f / sqrtf((float)od);
    c_dst[i] = 1.0f / sqrtf((float)id_);
}

// Merge 4 team sub-buckets into dense CSR (one wave per node).
__global__ __launch_bounds__(256) void compact_kernel(
    const unsigned* __restrict__ in4, const unsigned* __restrict__ col4,
    unsigned* __restrict__ colc, int total_waves)
{
    int wid  = (blockIdx.x * blockDim.x + threadIdx.x) >> 6;
    int lane = threadIdx.x & 63;
    for (int n = wid; n < N_NODES; n += total_waves) {
        unsigned off = 0;
#pragma unroll
        for (int t = 0; t < TEAMS; ++t) {
            unsigned dt = in4[t * N_NODES + n]; if (dt > TCAP) dt = TCAP;
            if ((unsigned)lane < dt) {
                unsigned v = col4[(size_t)n * (TEAMS * TCAP) + t * TCAP + lane];
                unsigned o = off + lane;
                if (o < CAPD) colc[(size_t)n * CAPD + o] = v;
            }
            off += dt;
        }
    }
}

// hs(bf16 pairs) = x * c_src[row]
__global__ __launch_bounds__(256) void prescale_kernel(
    const float2* __restrict__ x, const float* __restrict__ c_src,
    unsigned* __restrict__ hs)
{
    int i = blockIdx.x * blockDim.x + threadIdx.x;   // over N*64 uints
    if (i >= N_NODES * 64) return;
    int row = i >> 6;
    float c = c_src[row];
    float2 v = x[i];
    hs[i] = f2bf(v.x * c) | (f2bf(v.y * c) << 16);
}

// m[n] = sum over in-edges of hs[src]; 4-way unrolled gathers for MLP.
__global__ __launch_bounds__(256) void aggregate_kernel(
    const unsigned* __restrict__ hs, const unsigned* __restrict__ colc,
    const unsigned* __restrict__ cnt_tot, unsigned* __restrict__ m,
    int total_waves)
{
    int wid  = (blockIdx.x * blockDim.x + threadIdx.x) >> 6;
    int lane = threadIdx.x & 63;
    for (int n = wid; n < N_NODES; n += total_waves) {
        unsigned deg = cnt_tot[n]; if (deg > CAPD) deg = CAPD;
        const unsigned* cl = colc + (size_t)n * CAPD;
        float ax = 0.f, ay = 0.f;
        unsigned t = 0;
        for (; t + 4 <= deg; t += 4) {
            unsigned s0 = cl[t], s1 = cl[t + 1], s2 = cl[t + 2], s3 = cl[t + 3];
            unsigned u0 = hs[(size_t)s0 * 64 + lane];
            unsigned u1 = hs[(size_t)s1 * 64 + lane];
            unsigned u2 = hs[(size_t)s2 * 64 + lane];
            unsigned u3 = hs[(size_t)s3 * 64 + lane];
            ax += bf_lo(u0) + bf_lo(u1) + bf_lo(u2) + bf_lo(u3);
            ay += bf_hi(u0) + bf_hi(u1) + bf_hi(u2) + bf_hi(u3);
        }
        for (; t < deg; ++t) {
            unsigned u = hs[(size_t)cl[t] * 64 + lane];
            ax += bf_lo(u); ay += bf_hi(u);
        }
        m[(size_t)n * 64 + lane] = f2bf(ax) | (f2bf(ay) << 16);
    }
}

// Pre-swizzle W into MFMA B-fragment order, bf16.
__global__ __launch_bounds__(256) void wprep_kernel(
    const float* __restrict__ W0, const float* __restrict__ Ws,
    uint4* __restrict__ Wf)
{
    int t = blockIdx.x * blockDim.x + threadIdx.x;
    if (t >= NLAYER * 2048) return;
    int layer = t >> 11;
    int rem = t & 2047;
    int lane = rem & 63;
    int s = (rem >> 6) & 3;
    int c = rem >> 8;
    int quad = lane >> 4, colw = c * 16 + (lane & 15);
    int k0 = s * 32 + quad * 8;
    const float* W = (layer == 0) ? W0 : Ws + (size_t)(layer - 1) * DIM * DIM;
    uint4 p;
    unsigned* pp = (unsigned*)&p;
#pragma unroll
    for (int j = 0; j < 4; ++j) {
        unsigned lo = f2bf(W[(size_t)(k0 + 2 * j) * DIM + colw]);
        unsigned hi = f2bf(W[(size_t)(k0 + 2 * j + 1) * DIM + colw]);
        pp[j] = lo | (hi << 16);
    }
    Wf[t] = p;
}

// Hout = relu(c_dst[r]*(M@W) + b) [* c_src[r] if !last], MFMA 16x16x32 bf16.
__global__ __launch_bounds__(256) void mfma_gemm_kernel(
    const uint4* __restrict__ Mb, const uint4* __restrict__ Wf,
    const float* __restrict__ bias, const float* __restrict__ c_dst,
    const float* __restrict__ c_src, unsigned short* __restrict__ out_bf,
    float* __restrict__ out_f32, int last)
{
    int tid = threadIdx.x;
    int wave = tid >> 6, lane = tid & 63;
    int quad = lane >> 4, m16 = lane & 15;
    int r0 = blockIdx.x * 64 + wave * 16;

    int rA = r0 + m16; if (rA >= N_NODES) rA = N_NODES - 1;
    const uint4* pA = Mb + (size_t)rA * 16 + quad;
    union U { uint4 u; short8 s; };
    U a[4];
#pragma unroll
    for (int s = 0; s < 4; ++s) a[s].u = pA[s * 4];

    floatx4 acc[8];
#pragma unroll
    for (int c = 0; c < 8; ++c) {
        floatx4 ac = {0.f, 0.f, 0.f, 0.f};
#pragma unroll
        for (int s = 0; s < 4; ++s) {
            U b; b.u = Wf[(c * 4 + s) * 64 + lane];
            ac = __builtin_amdgcn_mfma_f32_16x16x32_bf16(a[s].s, b.s, ac, 0, 0, 0);
        }
        acc[c] = ac;
    }

    float cd[4], cs[4];
    int rows[4];
#pragma unroll
    for (int r = 0; r < 4; ++r) {
        int row = r0 + quad * 4 + r; rows[r] = row;
        bool ok = row < N_NODES;
        cd[r] = ok ? c_dst[row] : 0.f;
        cs[r] = (ok && !last) ? c_src[row] : 1.f;
    }
#pragma unroll
    for (int c = 0; c < 8; ++c) {
        int colg = c * 16 + m16;
        float b = bias[colg];
#pragma unroll
        for (int r = 0; r < 4; ++r) {
            int row = rows[r];
            if (row >= N_NODES) continue;
            float v = acc[c][r] * cd[r] + b;
            v = v > 0.f ? v : 0.f;
            if (last) out_f32[(size_t)row * DIM + colg] = v;
            else      out_bf[(size_t)row * DIM + colg] = (unsigned short)f2bf(v * cs[r]);
        }
    }
}

// Mean-pool readout on sorted graph_ids (fp32 h).
__global__ __launch_bounds__(128) void readout_kernel(
    const float* __restrict__ h, const int* __restrict__ gid,
    float* __restrict__ hg, float* __restrict__ cntg)
{
    int j  = threadIdx.x;
    int n0 = blockIdx.x * 64;
    float acc = 0.f; int cur = -1; int run = 0;
    for (int i = 0; i < 64; ++i) {
        int n = n0 + i;
        if (n >= N_NODES) break;
        int g = gid[n];
        if (g != cur) {
            if (cur >= 0) {
                atomicAdd(&hg[cur * DIM + j], acc);
                if (j == 0) atomicAdd(&cntg[cur], (float)run);
            }
            cur = g; acc = 0.f; run = 0;
        }
        acc += h[(size_t)n * DIM + j];
        run++;
    }
    if (cur >= 0) {
        atomicAdd(&hg[cur * DIM + j], acc);
        if (j == 0) atomicAdd(&cntg[cur], (float)run);
    }
}

__global__ __launch_bounds__(256) void head_kernel(
    const float* __restrict__ hg, const float* __restrict__ cntg,
    const float* __restrict__ Wc, const float* __restrict__ bc,
    float* __restrict__ out)
{
    int idx = blockIdx.x * blockDim.x + threadIdx.x;
    if (idx >= NGRAPH * NCLASS) return;
    int g = idx / NCLASS, c = idx % NCLASS;
    float inv = 1.0f / fmaxf(cntg[g], 1.0f);
    float s = 0.f;
    for (int j = 0; j < DIM; ++j) s = fmaf(hg[g * DIM + j], Wc[j * NCLASS + c], s);
    out[idx] = s * inv + bc[c];
}

// ---------------------------------------------------------------------------
extern "C" void kernel_launch(void* const* d_in, const int* in_sizes, int n_in,
                              void* d_out, int out_size, void* d_ws, size_t ws_size,
                              hipStream_t stream)
{
    const float* x   = (const float*)d_in[0];
    const float* W0  = (const float*)d_in[1];
    const float* b0  = (const float*)d_in[2];
    const float* Ws  = (const float*)d_in[3];
    const float* bs  = (const float*)d_in[4];
    const float* Wc  = (const float*)d_in[5];
    const float* bc  = (const float*)d_in[6];
    const int*   ei  = (const int*)d_in[7];
    const int*   gid = (const int*)d_in[8];
    float* out = (float*)d_out;

    char* ws = (char*)d_ws;
    size_t o = 0;
    auto alloc = [&](size_t bytes) {
        size_t r = o; o = (o + bytes + 255) & ~(size_t)255; return r;
    };
    unsigned* in4     = (unsigned*)(ws + alloc((size_t)TEAMS * N_NODES * 4));
    unsigned* out4    = (unsigned*)(ws + alloc((size_t)TEAMS * N_NODES * 4));
    unsigned* cnt_tot = (unsigned*)(ws + alloc((size_t)N_NODES * 4));
    float*    c_src   = (float*)(ws + alloc((size_t)N_NODES * 4));
    float*    c_dst   = (float*)(ws + alloc((size_t)N_NODES * 4));
    unsigned* col4    = (unsigned*)(ws + alloc((size_t)N_NODES * TEAMS * TCAP * 4));
    unsigned* colc    = (unsigned*)(ws + alloc((size_t)N_NODES * CAPD * 4));
    unsigned* hs      = (unsigned*)(ws + alloc((size_t)N_NODES * 64 * 4));  // bf16 x2
    unsigned* mbuf    = (unsigned*)(ws + alloc((size_t)N_NODES * 64 * 4));  // bf16 x2
    float*    hlast   = (float*)(ws + alloc((size_t)N_NODES * DIM * 4));
    uint4*    Wf      = (uint4*)(ws + alloc((size_t)NLAYER * 2048 * 16));
    float*    hg      = (float*)(ws + alloc((size_t)NGRAPH * DIM * 4));
    float*    cntg    = (float*)(ws + alloc((size_t)NGRAPH * 4));

    hipMemsetAsync(hg,   0, (size_t)NGRAPH * DIM * 4, stream);
    hipMemsetAsync(cntg, 0, (size_t)NGRAPH * 4, stream);

    part_build_kernel<<<TEAMS * NBT, 1024, 0, stream>>>(ei, out4, in4, col4);
    norm_kernel<<<(N_NODES + 255) / 256, 256, 0, stream>>>(out4, in4, c_src, c_dst, cnt_tot);
    compact_kernel<<<3125, 256, 0, stream>>>(in4, col4, colc, 12500);
    prescale_kernel<<<(N_NODES * 64 + 255) / 256, 256, 0, stream>>>(
        (const float2*)x, c_src, hs);
    wprep_kernel<<<(NLAYER * 2048 + 255) / 256, 256, 0, stream>>>(W0, Ws, Wf);

    const int AGG_BLOCKS = 2048;
    const int TOTAL_WAVES = AGG_BLOCKS * 4;
    const int GEMM_BLOCKS = (N_NODES + 63) / 64;

    for (int l = 0; l < NLAYER; ++l) {
        const float* b = (l == 0) ? b0 : (bs + (size_t)(l - 1) * DIM);
        int last = (l == NLAYER - 1) ? 1 : 0;
        aggregate_kernel<<<AGG_BLOCKS, 256, 0, stream>>>(hs, colc, cnt_tot, mbuf, TOTAL_WAVES);
        mfma_gemm_kernel<<<GEMM_BLOCKS, 256, 0, stream>>>(
            (const uint4*)mbuf, Wf + (size_t)l * 2048, b, c_dst, c_src,
            (unsigned short*)hs, hlast, last);
    }

    readout_kernel<<<(N_NODES + 63) / 64, 128, 0, stream>>>(hlast, gid, hg, cntg);
    head_kernel<<<(NGRAPH * NCLASS + 255) / 256, 256, 0, stream>>>(hg, cntg, Wc, bc, out);
}

// Round 4
// 352.577 us; speedup vs baseline: 2.0948x; 1.2147x over previous
//
#include <hip/hip_runtime.h>

#define N_NODES 50000
#define N_EDGES 800000
#define DIM     128
#define NGRAPH  128
#define NCLASS  10
#define N_HID   3
#define NLAYER  4

#define TEAMS   16
#define TCAP    12          // per-(node,team) cap; Poisson(1) tail ~6e-11
#define CAPD    64          // dense cap; Poisson(16) tail ~1e-18
#define NBT     16          // node-range blocks per team
#define RNG     3125        // N_NODES / NBT exactly

typedef __attribute__((ext_vector_type(8))) short short8;
typedef __attribute__((ext_vector_type(4))) float floatx4;

__device__ __forceinline__ unsigned f2bf(float f) {
    union { float f; unsigned u; } v; v.f = f;
    return (v.u + 0x7fffu + ((v.u >> 16) & 1u)) >> 16;   // RNE
}
__device__ __forceinline__ float bf_lo(unsigned u) { return __uint_as_float(u << 16); }
__device__ __forceinline__ float bf_hi(unsigned u) { return __uint_as_float(u & 0xffff0000u); }

// ---------------------------------------------------------------------------
// Privatized counting-sort build. Grid = TEAMS*NBT = 256 blocks x 1024.
// Block (team, nb): scans team's 50k-edge slice; LDS-histograms src/dst in
// its 3125-node range; scatters col entries into per-(node,team) sub-buckets.
__global__ __launch_bounds__(1024) void part_build_kernel(
    const int* __restrict__ ei, unsigned* __restrict__ out16,
    unsigned* __restrict__ in16, unsigned* __restrict__ col4)
{
    __shared__ unsigned loc_in[RNG], loc_out[RNG];
    int team = blockIdx.x >> 4;
    int nb   = blockIdx.x & 15;
    int lo = nb * RNG;
    for (int i = threadIdx.x; i < RNG; i += 1024) { loc_in[i] = 0; loc_out[i] = 0; }
    __syncthreads();

    const int e0 = team * (N_EDGES / TEAMS);
    const int e1 = e0 + (N_EDGES / TEAMS);
    const int* __restrict__ srcp = ei;
    const int* __restrict__ dstp = ei + N_EDGES;
    for (int e = e0 + threadIdx.x; e < e1; e += 1024) {
        int s = srcp[e];
        int d = dstp[e];
        unsigned su = (unsigned)(s - lo);
        unsigned du = (unsigned)(d - lo);
        if (su < RNG) atomicAdd(&loc_out[su], 1u);
        if (du < RNG) {
            unsigned pos = atomicAdd(&loc_in[du], 1u);
            if (pos < TCAP)
                col4[((size_t)d * TEAMS + team) * TCAP + pos] = (unsigned)s;
        }
    }
    __syncthreads();

    for (int i = threadIdx.x; i < RNG; i += 1024) {
        in16 [team * N_NODES + lo + i] = loc_in[i];
        out16[team * N_NODES + lo + i] = loc_out[i];
    }
}

// Sum team partials -> degrees -> norm coefficients.
__global__ __launch_bounds__(256) void norm_kernel(
    const unsigned* __restrict__ out16, const unsigned* __restrict__ in16,
    float* __restrict__ c_src, float* __restrict__ c_dst)
{
    int i = blockIdx.x * blockDim.x + threadIdx.x;
    if (i >= N_NODES) return;
    unsigned od = 0, id_ = 0;
#pragma unroll
    for (int t = 0; t < TEAMS; ++t) {
        od  += out16[t * N_NODES + i];
        id_ += in16 [t * N_NODES + i];
    }
    if (od < 1u) od = 1u;
    if (id_ < 1u) id_ = 1u;
    c_src[i] = 1.0f / sqrtf((float)od);
    c_dst[i] = 1.0f / sqrtf((float)id_);
}

// Merge 16 team sub-buckets into dense CSR. 16 lanes per node (4 nodes/wave):
// width-16 shfl prefix over team counts, parallel sub-copy, exact dense count.
__global__ __launch_bounds__(256) void compact_kernel(
    const unsigned* __restrict__ in16, const unsigned* __restrict__ col4,
    unsigned* __restrict__ colc, unsigned* __restrict__ cnt_dense)
{
    int gidx = (blockIdx.x * blockDim.x + threadIdx.x) >> 4;
    int t    = threadIdx.x & 15;
    if (gidx >= N_NODES) return;
    int n = gidx;
    unsigned c = in16[t * N_NODES + n]; if (c > TCAP) c = TCAP;
    unsigned incl = c;
#pragma unroll
    for (int d = 1; d < 16; d <<= 1) {
        unsigned o = __shfl_up(incl, d, 16);
        if (t >= d) incl += o;
    }
    unsigned excl = incl - c;
    const unsigned* sp = col4 + ((size_t)n * TEAMS + t) * TCAP;
    for (unsigned i = 0; i < c; ++i) {
        unsigned o = excl + i;
        if (o < CAPD) colc[(size_t)n * CAPD + o] = sp[i];
    }
    if (t == 15) {
        unsigned tot = incl; if (tot > CAPD) tot = CAPD;
        cnt_dense[n] = tot;
    }
}

// hs(bf16 pairs) = x * c_src[row]
__global__ __launch_bounds__(256) void prescale_kernel(
    const float2* __restrict__ x, const float* __restrict__ c_src,
    unsigned* __restrict__ hs)
{
    int i = blockIdx.x * blockDim.x + threadIdx.x;   // over N*64 uints
    if (i >= N_NODES * 64) return;
    int row = i >> 6;
    float c = c_src[row];
    float2 v = x[i];
    hs[i] = f2bf(v.x * c) | (f2bf(v.y * c) << 16);
}

// m[n] = sum over in-edges of hs[src]; neighbor indices loaded coalesced into
// lanes, broadcast via shfl; 8-way unrolled gathers.
__global__ __launch_bounds__(256) void aggregate_kernel(
    const unsigned* __restrict__ hs, const unsigned* __restrict__ colc,
    const unsigned* __restrict__ cnt_dense, unsigned* __restrict__ m,
    int total_waves)
{
    int wid  = (blockIdx.x * blockDim.x + threadIdx.x) >> 6;
    int lane = threadIdx.x & 63;
    for (int n = wid; n < N_NODES; n += total_waves) {
        unsigned deg = cnt_dense[n];
        unsigned myidx = colc[(size_t)n * CAPD + lane];   // coalesced 256B
        float ax = 0.f, ay = 0.f;
        unsigned t = 0;
        for (; t + 8 <= deg; t += 8) {
            unsigned s0 = __shfl(myidx, (int)t);
            unsigned s1 = __shfl(myidx, (int)t + 1);
            unsigned s2 = __shfl(myidx, (int)t + 2);
            unsigned s3 = __shfl(myidx, (int)t + 3);
            unsigned s4 = __shfl(myidx, (int)t + 4);
            unsigned s5 = __shfl(myidx, (int)t + 5);
            unsigned s6 = __shfl(myidx, (int)t + 6);
            unsigned s7 = __shfl(myidx, (int)t + 7);
            unsigned u0 = hs[(size_t)s0 * 64 + lane];
            unsigned u1 = hs[(size_t)s1 * 64 + lane];
            unsigned u2 = hs[(size_t)s2 * 64 + lane];
            unsigned u3 = hs[(size_t)s3 * 64 + lane];
            unsigned u4 = hs[(size_t)s4 * 64 + lane];
            unsigned u5 = hs[(size_t)s5 * 64 + lane];
            unsigned u6 = hs[(size_t)s6 * 64 + lane];
            unsigned u7 = hs[(size_t)s7 * 64 + lane];
            ax += bf_lo(u0) + bf_lo(u1) + bf_lo(u2) + bf_lo(u3)
                + bf_lo(u4) + bf_lo(u5) + bf_lo(u6) + bf_lo(u7);
            ay += bf_hi(u0) + bf_hi(u1) + bf_hi(u2) + bf_hi(u3)
                + bf_hi(u4) + bf_hi(u5) + bf_hi(u6) + bf_hi(u7);
        }
        for (; t + 4 <= deg; t += 4) {
            unsigned s0 = __shfl(myidx, (int)t);
            unsigned s1 = __shfl(myidx, (int)t + 1);
            unsigned s2 = __shfl(myidx, (int)t + 2);
            unsigned s3 = __shfl(myidx, (int)t + 3);
            unsigned u0 = hs[(size_t)s0 * 64 + lane];
            unsigned u1 = hs[(size_t)s1 * 64 + lane];
            unsigned u2 = hs[(size_t)s2 * 64 + lane];
            unsigned u3 = hs[(size_t)s3 * 64 + lane];
            ax += bf_lo(u0) + bf_lo(u1) + bf_lo(u2) + bf_lo(u3);
            ay += bf_hi(u0) + bf_hi(u1) + bf_hi(u2) + bf_hi(u3);
        }
        for (; t < deg; ++t) {
            unsigned s0 = __shfl(myidx, (int)t);
            unsigned u = hs[(size_t)s0 * 64 + lane];
            ax += bf_lo(u); ay += bf_hi(u);
        }
        m[(size_t)n * 64 + lane] = f2bf(ax) | (f2bf(ay) << 16);
    }
}

// Pre-swizzle W into MFMA B-fragment order, bf16.
__global__ __launch_bounds__(256) void wprep_kernel(
    const float* __restrict__ W0, const float* __restrict__ Ws,
    uint4* __restrict__ Wf)
{
    int t = blockIdx.x * blockDim.x + threadIdx.x;
    if (t >= NLAYER * 2048) return;
    int layer = t >> 11;
    int rem = t & 2047;
    int lane = rem & 63;
    int s = (rem >> 6) & 3;
    int c = rem >> 8;
    int quad = lane >> 4, colw = c * 16 + (lane & 15);
    int k0 = s * 32 + quad * 8;
    const float* W = (layer == 0) ? W0 : Ws + (size_t)(layer - 1) * DIM * DIM;
    uint4 p;
    unsigned* pp = (unsigned*)&p;
#pragma unroll
    for (int j = 0; j < 4; ++j) {
        unsigned lo = f2bf(W[(size_t)(k0 + 2 * j) * DIM + colw]);
        unsigned hi = f2bf(W[(size_t)(k0 + 2 * j + 1) * DIM + colw]);
        pp[j] = lo | (hi << 16);
    }
    Wf[t] = p;
}

// Hout = relu(c_dst[r]*(M@W) + b) [* c_src[r] if !last], MFMA 16x16x32 bf16.
__global__ __launch_bounds__(256) void mfma_gemm_kernel(
    const uint4* __restrict__ Mb, const uint4* __restrict__ Wf,
    const float* __restrict__ bias, const float* __restrict__ c_dst,
    const float* __restrict__ c_src, unsigned short* __restrict__ out_bf,
    float* __restrict__ out_f32, int last)
{
    int tid = threadIdx.x;
    int wave = tid >> 6, lane = tid & 63;
    int quad = lane >> 4, m16 = lane & 15;
    int r0 = blockIdx.x * 64 + wave * 16;

    int rA = r0 + m16; if (rA >= N_NODES) rA = N_NODES - 1;
    const uint4* pA = Mb + (size_t)rA * 16 + quad;
    union U { uint4 u; short8 s; };
    U a[4];
#pragma unroll
    for (int s = 0; s < 4; ++s) a[s].u = pA[s * 4];

    floatx4 acc[8];
#pragma unroll
    for (int c = 0; c < 8; ++c) {
        floatx4 ac = {0.f, 0.f, 0.f, 0.f};
#pragma unroll
        for (int s = 0; s < 4; ++s) {
            U b; b.u = Wf[(c * 4 + s) * 64 + lane];
            ac = __builtin_amdgcn_mfma_f32_16x16x32_bf16(a[s].s, b.s, ac, 0, 0, 0);
        }
        acc[c] = ac;
    }

    float cd[4], cs[4];
    int rows[4];
#pragma unroll
    for (int r = 0; r < 4; ++r) {
        int row = r0 + quad * 4 + r; rows[r] = row;
        bool ok = row < N_NODES;
        cd[r] = ok ? c_dst[row] : 0.f;
        cs[r] = (ok && !last) ? c_src[row] : 1.f;
    }
#pragma unroll
    for (int c = 0; c < 8; ++c) {
        int colg = c * 16 + m16;
        float b = bias[colg];
#pragma unroll
        for (int r = 0; r < 4; ++r) {
            int row = rows[r];
            if (row >= N_NODES) continue;
            float v = acc[c][r] * cd[r] + b;
            v = v > 0.f ? v : 0.f;
            if (last) out_f32[(size_t)row * DIM + colg] = v;
            else      out_bf[(size_t)row * DIM + colg] = (unsigned short)f2bf(v * cs[r]);
        }
    }
}

// Mean-pool readout on sorted graph_ids (fp32 h).
__global__ __launch_bounds__(128) void readout_kernel(
    const float* __restrict__ h, const int* __restrict__ gid,
    float* __restrict__ hg, float* __restrict__ cntg)
{
    int j  = threadIdx.x;
    int n0 = blockIdx.x * 64;
    float acc = 0.f; int cur = -1; int run = 0;
    for (int i = 0; i < 64; ++i) {
        int n = n0 + i;
        if (n >= N_NODES) break;
        int g = gid[n];
        if (g != cur) {
            if (cur >= 0) {
                atomicAdd(&hg[cur * DIM + j], acc);
                if (j == 0) atomicAdd(&cntg[cur], (float)run);
            }
            cur = g; acc = 0.f; run = 0;
        }
        acc += h[(size_t)n * DIM + j];
        run++;
    }
    if (cur >= 0) {
        atomicAdd(&hg[cur * DIM + j], acc);
        if (j == 0) atomicAdd(&cntg[cur], (float)run);
    }
}

__global__ __launch_bounds__(256) void head_kernel(
    const float* __restrict__ hg, const float* __restrict__ cntg,
    const float* __restrict__ Wc, const float* __restrict__ bc,
    float* __restrict__ out)
{
    int idx = blockIdx.x * blockDim.x + threadIdx.x;
    if (idx >= NGRAPH * NCLASS) return;
    int g = idx / NCLASS, c = idx % NCLASS;
    float inv = 1.0f / fmaxf(cntg[g], 1.0f);
    float s = 0.f;
    for (int j = 0; j < DIM; ++j) s = fmaf(hg[g * DIM + j], Wc[j * NCLASS + c], s);
    out[idx] = s * inv + bc[c];
}

// ---------------------------------------------------------------------------
extern "C" void kernel_launch(void* const* d_in, const int* in_sizes, int n_in,
                              void* d_out, int out_size, void* d_ws, size_t ws_size,
                              hipStream_t stream)
{
    const float* x   = (const float*)d_in[0];
    const float* W0  = (const float*)d_in[1];
    const float* b0  = (const float*)d_in[2];
    const float* Ws  = (const float*)d_in[3];
    const float* bs  = (const float*)d_in[4];
    const float* Wc  = (const float*)d_in[5];
    const float* bc  = (const float*)d_in[6];
    const int*   ei  = (const int*)d_in[7];
    const int*   gid = (const int*)d_in[8];
    float* out = (float*)d_out;

    char* ws = (char*)d_ws;
    size_t o = 0;
    auto alloc = [&](size_t bytes) {
        size_t r = o; o = (o + bytes + 255) & ~(size_t)255; return r;
    };
    unsigned* in16      = (unsigned*)(ws + alloc((size_t)TEAMS * N_NODES * 4));
    unsigned* out16     = (unsigned*)(ws + alloc((size_t)TEAMS * N_NODES * 4));
    unsigned* cnt_dense = (unsigned*)(ws + alloc((size_t)N_NODES * 4));
    float*    c_src     = (float*)(ws + alloc((size_t)N_NODES * 4));
    float*    c_dst     = (float*)(ws + alloc((size_t)N_NODES * 4));
    // col4 (38.4MB, dead after compact) shares space with hlast (25.6MB).
    size_t big_off      = alloc((size_t)N_NODES * TEAMS * TCAP * 4);
    unsigned* col4      = (unsigned*)(ws + big_off);
    float*    hlast     = (float*)(ws + big_off);
    unsigned* colc      = (unsigned*)(ws + alloc((size_t)N_NODES * CAPD * 4));
    unsigned* hs        = (unsigned*)(ws + alloc((size_t)N_NODES * 64 * 4));
    unsigned* mbuf      = (unsigned*)(ws + alloc((size_t)N_NODES * 64 * 4));
    uint4*    Wf        = (uint4*)(ws + alloc((size_t)NLAYER * 2048 * 16));
    float*    hg        = (float*)(ws + alloc((size_t)NGRAPH * DIM * 4));
    float*    cntg      = (float*)(ws + alloc((size_t)NGRAPH * 4));

    hipMemsetAsync(hg,   0, (size_t)NGRAPH * DIM * 4, stream);
    hipMemsetAsync(cntg, 0, (size_t)NGRAPH * 4, stream);

    part_build_kernel<<<TEAMS * NBT, 1024, 0, stream>>>(ei, out16, in16, col4);
    norm_kernel<<<(N_NODES + 255) / 256, 256, 0, stream>>>(out16, in16, c_src, c_dst);
    compact_kernel<<<(N_NODES * 16 + 255) / 256, 256, 0, stream>>>(
        in16, col4, colc, cnt_dense);
    prescale_kernel<<<(N_NODES * 64 + 255) / 256, 256, 0, stream>>>(
        (const float2*)x, c_src, hs);
    wprep_kernel<<<(NLAYER * 2048 + 255) / 256, 256, 0, stream>>>(W0, Ws, Wf);

    const int AGG_BLOCKS = 2048;
    const int TOTAL_WAVES = AGG_BLOCKS * 4;
    const int GEMM_BLOCKS = (N_NODES + 63) / 64;

    for (int l = 0; l < NLAYER; ++l) {
        const float* b = (l == 0) ? b0 : (bs + (size_t)(l - 1) * DIM);
        int last = (l == NLAYER - 1) ? 1 : 0;
        aggregate_kernel<<<AGG_BLOCKS, 256, 0, stream>>>(
            hs, colc, cnt_dense, mbuf, TOTAL_WAVES);
        mfma_gemm_kernel<<<GEMM_BLOCKS, 256, 0, stream>>>(
            (const uint4*)mbuf, Wf + (size_t)l * 2048, b, c_dst, c_src,
            (unsigned short*)hs, hlast, last);
    }

    readout_kernel<<<(N_NODES + 63) / 64, 128, 0, stream>>>(hlast, gid, hg, cntg);
    head_kernel<<<(NGRAPH * NCLASS + 255) / 256, 256, 0, stream>>>(hg, cntg, Wc, bc, out);
}